// Round 12
// baseline (163.889 us; speedup 1.0000x reference)
//
#include <hip/hip_runtime.h>
#include <hip/hip_bf16.h>
#include <math.h>

#define N_PTS 50000
#define CCH   64
#define KP    15
#define NH    32
#define SIGMA 0.7f
#define BN_EPS 1e-5f
#define LEAKY 0.1f
#define QB    16
#define CWS   18           // cwT row stride in bf16 (16 q + 2 pad -> 2-way banks, free)
#define STATS_BLOCKS 1024
#define W2P_BLOCKS   30
#define QC           64    // queries per classification block
#define CLS_BLOCKS   782   // ceil(50000/64)
#define PACK_BLOCKS  196   // ceil(50000/256)

typedef short bf16x8 __attribute__((ext_vector_type(8)));
typedef float floatx4 __attribute__((ext_vector_type(4)));

__device__ __forceinline__ unsigned short f2b(float f) {
    union { float f; unsigned u; } v; v.f = f;
    return (unsigned short)((v.u + 0x7FFFu + ((v.u >> 16) & 1u)) >> 16);  // RNE
}
__device__ __forceinline__ ushort2 f2b2(float a, float b) {   // v_cvt_pk_bf16_f32
    __hip_bfloat162 h = __float22bfloat162_rn(float2{a, b});
    union { __hip_bfloat162 h; ushort2 u; } v; v.h = h;
    return v.u;
}
__device__ __forceinline__ float b2f(unsigned short b) {
    union { unsigned u; float f; } v; v.u = ((unsigned)b) << 16;
    return v.f;
}

// ---------- K0: pad s_pts (12B rows) into float4 table (16B rows) so the cls
//             gather is ONE dwordx4 txn per neighbor instead of 3 dword txns. ----------
__global__ __launch_bounds__(256) void k_pack4(const float* __restrict__ sp,
                                               float4* __restrict__ sp4) {
    int i = blockIdx.x * 256 + threadIdx.x;
    if (i < N_PTS) {
        float4 v;
        v.x = sp[i * 3 + 0]; v.y = sp[i * 3 + 1]; v.z = sp[i * 3 + 2]; v.w = 0.f;
        sp4[i] = v;
    }
}

// ---------- K1: [0,1024) stats: h = sf@W1 -> hst bf16 + BN sums + sfb shadow.
//             [1024,1054) W2 repack.  [1054,1836) neighbor classification. ----------
__global__ __launch_bounds__(256) void k_prep(const float* __restrict__ sf,
                                              const float* __restrict__ W1,
                                              const float* __restrict__ W2,
                                              const float* __restrict__ q_pts,
                                              const float4* __restrict__ sp4,
                                              const int* __restrict__ nb,
                                              const float* __restrict__ kpts,
                                              float* __restrict__ bn,
                                              unsigned short* __restrict__ hst,
                                              unsigned short* __restrict__ w2b,
                                              unsigned short* __restrict__ sfb,
                                              unsigned* __restrict__ packG,
                                              int* __restrict__ cntG) {
    int t = threadIdx.x;
    if (blockIdx.x >= STATS_BLOCKS + W2P_BLOCKS) {
        // ---- neighbor classification: batched loads, ballot compaction,
        //      LDS-staged COALESCED packG writeout (kills write scatter) ----
        int q0 = (blockIdx.x - (STATS_BLOCKS + W2P_BLOCKS)) * QC;
        int lane = t & 63, lh = lane & 31;
        __shared__ unsigned cbuf[QC * NH];   // 8 KB staging
        __shared__ int      ccnt[QC];

        // batch 1: 8 neighbor indices (coalesced)
        int idx8[8];
        #pragma unroll
        for (int r = 0; r < 8; ++r) {
            int task = t + r * 256;               // task = ql*32 + hh
            int m = q0 + (task >> 5);
            idx8[r] = (m < N_PTS) ? nb[m * NH + (task & 31)] : 0;
        }
        // batch 2: 8 float4 gathers (ONE txn each) + q_pts broadcasts, in flight
        float4 sv[8]; float qx[8], qy[8], qz[8];
        #pragma unroll
        for (int r = 0; r < 8; ++r) {
            int m = q0 + ((t + r * 256) >> 5);
            int mm = (m < N_PTS) ? m : 0;
            sv[r] = sp4[idx8[r]];
            qx[r] = q_pts[mm * 3 + 0];            // 2 addrs/wave: broadcast-cheap
            qy[r] = q_pts[mm * 3 + 1];
            qz[r] = q_pts[mm * 3 + 2];
        }
        float kpr[45];
        #pragma unroll
        for (int i = 0; i < 45; ++i) kpr[i] = kpts[i];   // uniform -> s_loads

        #pragma unroll
        for (int r = 0; r < 8; ++r) {
            int task = t + r * 256;
            int ql = task >> 5;                   // local query 0..63
            bool valid = (q0 + ql < N_PTS);
            float px = sv[r].x - qx[r], py = sv[r].y - qy[r], pz = sv[r].z - qz[r];
            float best = 1e30f; int bi = 0;
            #pragma unroll
            for (int k = 0; k < KP; ++k) {
                float dx = px - kpr[k*3], dy = py - kpr[k*3+1], dz = pz - kpr[k*3+2];
                float d = dx * dx + dy * dy + dz * dz;
                if (d < best) { best = d; bi = k; }
            }
            float infl = 1.f - sqrtf(best) * (1.0f / SIGMA);
            bool act = valid && (infl > 0.f);
            unsigned long long bal = __ballot(act);
            unsigned m32 = (unsigned)(bal >> (lane & 32));   // half-wave mask
            int prefix = __popc(m32 & ((1u << lh) - 1u));
            int cntq   = __popc(m32);
            int slot   = act ? prefix : cntq + (lh - prefix);  // permutation of 0..31
            int iq = (int)(infl * 4095.f + 0.5f);
            unsigned val = act ? ((unsigned)idx8[r] | ((unsigned)bi << 16)
                                  | ((unsigned)iq << 20)) : 0u;
            cbuf[ql * NH + slot] = val;           // every slot written exactly once
            if (lh == 0) ccnt[ql] = cntq;
        }
        __syncthreads();
        // coalesced writeout: 2048 dwords as 512 uint4 stores
        #pragma unroll
        for (int i = 0; i < 2; ++i) {
            int di = (t + i * 256) * 4;           // dword idx, row = di>>5 (uint4 stays in-row)
            if (q0 + (di >> 5) < N_PTS)
                *(uint4*)(packG + q0 * NH + di) = *(const uint4*)(cbuf + di);
        }
        if (t < QC && q0 + t < N_PTS) cntG[q0 + t] = ccnt[t];
        return;
    }
    if (blockIdx.x >= STATS_BLOCKS) {
        // w2b[((tile*2+kstep)*64+lane)*8+j] = bf16(W2[k][n]),
        //   k = kstep*32 + (lane>>4)*8 + j, n = tile*16 + (lane&15)
        int g = (blockIdx.x - STATS_BLOCKS) * 256 + t;   // 7680 exactly
        int lane = g & 63, s = (g >> 6) & 1, tt = g >> 7;
        int col = lane & 15, quad = lane >> 4;
        int base = (s * 32 + quad * 8) * 960 + tt * 16 + col;
        ushort4 lo, hi;
        lo.x = f2b(W2[base + 0 * 960]); lo.y = f2b(W2[base + 1 * 960]);
        lo.z = f2b(W2[base + 2 * 960]); lo.w = f2b(W2[base + 3 * 960]);
        hi.x = f2b(W2[base + 4 * 960]); hi.y = f2b(W2[base + 5 * 960]);
        hi.z = f2b(W2[base + 6 * 960]); hi.w = f2b(W2[base + 7 * 960]);
        *(ushort4*)(w2b + g * 8)     = lo;
        *(ushort4*)(w2b + g * 8 + 4) = hi;
        return;
    }
    int c = t & 63, ml = t >> 6;
    float w1c[64];
    #pragma unroll
    for (int i = 0; i < 64; ++i) w1c[i] = W1[i * 64 + c];
    __shared__ float rows[4][64];
    float acc_s = 0.f, acc_q = 0.f;
    for (int m0 = blockIdx.x * 4; m0 < N_PTS; m0 += STATS_BLOCKS * 4) {
        __syncthreads();
        float v = sf[m0 * 64 + t];
        ((float*)rows)[t] = v;
        sfb[m0 * 64 + t] = f2b(v);             // bf16 shadow for phase-B gathers
        __syncthreads();
        float h = 0.f;
        #pragma unroll
        for (int i4 = 0; i4 < 16; ++i4) {
            float4 r = *(const float4*)&rows[ml][i4 * 4];
            h += r.x * w1c[i4 * 4] + r.y * w1c[i4 * 4 + 1]
               + r.z * w1c[i4 * 4 + 2] + r.w * w1c[i4 * 4 + 3];
        }
        acc_s += h;
        acc_q += h * h;
        hst[(m0 + ml) * 64 + c] = f2b(h);      // 128B/wave coalesced
    }
    __shared__ float red[2][256];
    red[0][t] = acc_s; red[1][t] = acc_q;
    __syncthreads();
    if (t < 64) {
        float s = red[0][t] + red[0][64 + t] + red[0][128 + t] + red[0][192 + t];
        float q = red[1][t] + red[1][64 + t] + red[1][128 + t] + red[1][192 + t];
        atomicAdd(&bn[t], s);
        atomicAdd(&bn[64 + t], q);
    }
}

// ---------- K2: fused main. 256 threads / 4 waves — the proven round-3 shape. ----------
__global__ __launch_bounds__(256, 4) void k_main(
    const unsigned short* __restrict__ sfb,
    const float* __restrict__ gamma, const float* __restrict__ beta,
    const float* __restrict__ bn, const float* __restrict__ b2,
    const unsigned short* __restrict__ w2b, const unsigned short* __restrict__ hst,
    const unsigned* __restrict__ packG, const int* __restrict__ cntG,
    float* __restrict__ out) {

    __shared__ __align__(16) unsigned short cwT[960 * CWS];  // 34.56 KB: cw[n][q] bf16
    __shared__ float abS[128];                               // BN fold a[64], b[64]

    int t = threadIdx.x;
    int lane = t & 63, wv = t >> 6;
    int m0 = blockIdx.x * QB;

    if (t < 64) {   // inline BN finalize
        float mu  = bn[t] * (1.0f / N_PTS);
        float var = bn[64 + t] * (1.0f / N_PTS) - mu * mu;
        float a   = gamma[t] * rsqrtf(var + BN_EPS);
        abS[t]      = a;
        abS[64 + t] = beta[t] - mu * a;
    }
    __syncthreads();

    // ---- A-fragments directly in registers: fold BN + leaky on bf16 h rows ----
    int row = lane & 15, half = lane >> 4;
    bf16x8 a0, a1;
    {
        const unsigned short* hrow = hst + (m0 + row) * 64 + half * 8;
        bf16x8 r0 = *(const bf16x8*)(hrow);        // c = half*8 + j
        bf16x8 r1 = *(const bf16x8*)(hrow + 32);   // c = 32 + half*8 + j
        #pragma unroll
        for (int j = 0; j < 8; j += 2) {
            int c0 = half * 8 + j;
            float g0 = abS[c0] * b2f((unsigned short)r0[j]) + abS[64 + c0];
            float g1 = abS[c0 + 1] * b2f((unsigned short)r0[j + 1]) + abS[64 + c0 + 1];
            g0 = g0 > 0.f ? g0 : LEAKY * g0;
            g1 = g1 > 0.f ? g1 : LEAKY * g1;
            ushort2 p01 = f2b2(g0, g1);
            a0[j] = (short)p01.x; a0[j + 1] = (short)p01.y;
            int c1 = 32 + c0;
            float g2 = abS[c1] * b2f((unsigned short)r1[j]) + abS[64 + c1];
            float g3 = abS[c1 + 1] * b2f((unsigned short)r1[j + 1]) + abS[64 + c1 + 1];
            g2 = g2 > 0.f ? g2 : LEAKY * g2;
            g3 = g3 > 0.f ? g3 : LEAKY * g3;
            ushort2 p23 = f2b2(g2, g3);
            a1[j] = (short)p23.x; a1[j + 1] = (short)p23.y;
        }
    }

    // ---- phase A: cw = G @ W2 via MFMA; each wave owns 15 n-tiles ----
    {
        int col = lane & 15, quad = lane >> 4;
        for (int ti = 0; ti < 15; ++ti) {
            int tt = wv * 15 + ti;
            bf16x8 bf0 = *(const bf16x8*)(w2b + ((tt * 2 + 0) * 64 + lane) * 8);
            bf16x8 bf1 = *(const bf16x8*)(w2b + ((tt * 2 + 1) * 64 + lane) * 8);
            floatx4 acc = {0.f, 0.f, 0.f, 0.f};
            acc = __builtin_amdgcn_mfma_f32_16x16x32_bf16(a0, bf0, acc, 0, 0, 0);
            acc = __builtin_amdgcn_mfma_f32_16x16x32_bf16(a1, bf1, acc, 0, 0, 0);
            int n = tt * 16 + col;
            float bb = b2[n];
            unsigned short* dst = &cwT[n * CWS + quad * 4];   // D: row(q)=quad*4+reg
            ushort2 w01 = f2b2(acc[0] + bb, acc[1] + bb);     // v_cvt_pk_bf16_f32
            ushort2 w23 = f2b2(acc[2] + bb, acc[3] + bb);
            *(ushort2*)(dst)     = w01;
            *(ushort2*)(dst + 2) = w23;
        }
    }
    __syncthreads();

    // ---- phase B: wave owns 4 queries as 2 pairs; 4-wide interleave.
    //      List reads are wave-uniform (readfirstlane) -> scalar s_loads. ----
    {
        int wvu = __builtin_amdgcn_readfirstlane(wv);
        int c = lane;
        #pragma unroll
        for (int pp = 0; pp < 2; ++pp) {
            int qa = wvu * 4 + pp * 2, qb = qa + 1;
            int ma = m0 + qa, mb = m0 + qb;
            const unsigned* pA = packG + ma * NH;
            const unsigned* pB = packG + mb * NH;
            const unsigned short* cwa = cwT + c * CWS + qa;   // per-lane cw base
            const unsigned short* cwb = cwa + 1;
            int cA = cntG[ma], cB = cntG[mb];                 // uniform -> s_load
            int na = cA > cB ? cA : cB;
            na = (na + 3) & ~3;                               // slots < 32 are zeroed
            float accA = 0.f, accB = 0.f;
            for (int jj = 0; jj < na; jj += 4) {
                unsigned pa0 = pA[jj], pa1 = pA[jj+1], pa2 = pA[jj+2], pa3 = pA[jj+3];
                unsigned pb0 = pB[jj], pb1 = pB[jj+1], pb2 = pB[jj+2], pb3 = pB[jj+3];
                // 8 independent bf16 gathers
                float fA0 = b2f(sfb[(pa0 & 0xFFFFu) * 64 + c]);
                float fA1 = b2f(sfb[(pa1 & 0xFFFFu) * 64 + c]);
                float fA2 = b2f(sfb[(pa2 & 0xFFFFu) * 64 + c]);
                float fA3 = b2f(sfb[(pa3 & 0xFFFFu) * 64 + c]);
                float fB0 = b2f(sfb[(pb0 & 0xFFFFu) * 64 + c]);
                float fB1 = b2f(sfb[(pb1 & 0xFFFFu) * 64 + c]);
                float fB2 = b2f(sfb[(pb2 & 0xFFFFu) * 64 + c]);
                float fB3 = b2f(sfb[(pb3 & 0xFFFFu) * 64 + c]);
                // 8 LDS reads (k*64*CWS offset from scalar field)
                float wA0 = b2f(cwa[((pa0 >> 16) & 15u) * (64 * CWS)]);
                float wA1 = b2f(cwa[((pa1 >> 16) & 15u) * (64 * CWS)]);
                float wA2 = b2f(cwa[((pa2 >> 16) & 15u) * (64 * CWS)]);
                float wA3 = b2f(cwa[((pa3 >> 16) & 15u) * (64 * CWS)]);
                float wB0 = b2f(cwb[((pb0 >> 16) & 15u) * (64 * CWS)]);
                float wB1 = b2f(cwb[((pb1 >> 16) & 15u) * (64 * CWS)]);
                float wB2 = b2f(cwb[((pb2 >> 16) & 15u) * (64 * CWS)]);
                float wB3 = b2f(cwb[((pb3 >> 16) & 15u) * (64 * CWS)]);
                // q12 influence from scalar field
                float iA0 = (float)(pa0 >> 20), iA1 = (float)(pa1 >> 20);
                float iA2 = (float)(pa2 >> 20), iA3 = (float)(pa3 >> 20);
                float iB0 = (float)(pb0 >> 20), iB1 = (float)(pb1 >> 20);
                float iB2 = (float)(pb2 >> 20), iB3 = (float)(pb3 >> 20);
                accA += iA0 * fA0 * wA0 + iA1 * fA1 * wA1
                      + iA2 * fA2 * wA2 + iA3 * fA3 * wA3;
                accB += iB0 * fB0 * wB0 + iB1 * fB1 * wB1
                      + iB2 * fB2 * wB2 + iB3 * fB3 * wB3;
            }
            const float qs = 1.f / 4095.f;
            out[ma * 64 + c] = accA * qs;
            out[mb * 64 + c] = accB * qs;
        }
    }
}

extern "C" void kernel_launch(void* const* d_in, const int* in_sizes, int n_in,
                              void* d_out, int out_size, void* d_ws, size_t ws_size,
                              hipStream_t stream) {
    const float* q_pts   = (const float*)d_in[0];
    const float* s_pts   = (const float*)d_in[1];
    const float* s_feats = (const float*)d_in[2];
    const int*   nb      = (const int*)d_in[3];
    const float* kpts    = (const float*)d_in[4];
    const float* W1      = (const float*)d_in[5];
    const float* gamma   = (const float*)d_in[6];
    const float* beta    = (const float*)d_in[7];
    const float* W2      = (const float*)d_in[8];
    const float* b2      = (const float*)d_in[9];
    float* out = (float*)d_out;

    float* ws = (float*)d_ws;
    float* bn = ws;                                        // 128 fp32
    unsigned short* w2b = (unsigned short*)(ws + 128);     // 61440 bf16 (122880 B)
    unsigned short* hst = w2b + 61440;                     // 50000*64 bf16 (6.4 MB)
    unsigned short* sfb = hst + N_PTS * CCH;               // 50000*64 bf16 (6.4 MB)
    unsigned* packG = (unsigned*)(sfb + N_PTS * CCH);      // 50000*32 u32 (6.4 MB)
    int* cntG = (int*)(packG + N_PTS * NH);                // 50000 int (200 KB)
    float4* sp4 = (float4*)(cntG + ((N_PTS + 3) & ~3));    // 50000 float4 (800 KB)

    hipMemsetAsync(bn, 0, 128 * sizeof(float), stream);
    k_pack4<<<PACK_BLOCKS, 256, 0, stream>>>(s_pts, sp4);
    k_prep<<<STATS_BLOCKS + W2P_BLOCKS + CLS_BLOCKS, 256, 0, stream>>>(
        s_feats, W1, W2, q_pts, sp4, nb, kpts, bn, hst, w2b, sfb, packG, cntG);
    k_main<<<N_PTS / QB, 256, 0, stream>>>(sfb, gamma, beta, bn, b2, w2b, hst,
                                           packG, cntG, out);
}

// Round 13
// 162.859 us; speedup vs baseline: 1.0063x; 1.0063x over previous
//
#include <hip/hip_runtime.h>
#include <hip/hip_bf16.h>
#include <math.h>

#define N_PTS 50000
#define CCH   64
#define KP    15
#define NH    32
#define SIGMA 0.7f
#define BN_EPS 1e-5f
#define LEAKY 0.1f
#define QB    16
#define CWS   18           // cwT row stride in bf16 (16 q + 2 pad -> 2-way banks, free)
#define STATS_BLOCKS 1024
#define QC           64    // queries per classification block
#define CLS_BLOCKS   782   // ceil(50000/64)
#define PACK_BLOCKS  196   // ceil(50000/256) for pack4 part of k_misc

typedef short bf16x8 __attribute__((ext_vector_type(8)));
typedef float floatx4 __attribute__((ext_vector_type(4)));

__device__ __forceinline__ unsigned short f2b(float f) {
    union { float f; unsigned u; } v; v.f = f;
    return (unsigned short)((v.u + 0x7FFFu + ((v.u >> 16) & 1u)) >> 16);  // RNE
}
__device__ __forceinline__ ushort2 f2b2(float a, float b) {   // v_cvt_pk_bf16_f32
    __hip_bfloat162 h = __float22bfloat162_rn(float2{a, b});
    union { __hip_bfloat162 h; ushort2 u; } v; v.h = h;
    return v.u;
}
__device__ __forceinline__ float b2f(unsigned short b) {
    union { unsigned u; float f; } v; v.u = ((unsigned)b) << 16;
    return v.f;
}

// ---------- K0 (k_misc): blocks [0,197): pack s_pts->float4 (+ block0: zero bn).
//            blocks [197,257): W2 repack, LDS-staged (kills 64-line divergent reads). ----------
__global__ __launch_bounds__(256) void k_misc(const float* __restrict__ sp,
                                              const float* __restrict__ W2,
                                              float4* __restrict__ sp4,
                                              unsigned short* __restrict__ w2b,
                                              float* __restrict__ bn) {
    int t = threadIdx.x;
    if (blockIdx.x >= PACK_BLOCKS + 1) {
        // ---- W2 repack, one 16-col tile per block ----
        int tt = blockIdx.x - (PACK_BLOCKS + 1);          // 0..59
        __shared__ float ld[64 * 16];                     // ld[k*16+col]
        {   // coalesced-ish stage: thread t loads float4, (k = t>>2, colg = t&3)
            int k = t >> 2, colg = t & 3;
            *(float4*)&ld[k * 16 + colg * 4] =
                *(const float4*)&W2[k * 960 + tt * 16 + colg * 4];
        }
        __syncthreads();
        if (t < 128) {                                    // s = t>>6, lane = t&63
            int s = t >> 6, lane = t & 63;
            int quad = lane >> 4, col = lane & 15;
            unsigned short v[8];
            #pragma unroll
            for (int j = 0; j < 8; ++j)
                v[j] = f2b(ld[(s * 32 + quad * 8 + j) * 16 + col]);
            unsigned short* dst = w2b + ((tt * 2 + s) * 64 + lane) * 8;
            *(ushort4*)(dst)     = ushort4{v[0], v[1], v[2], v[3]};
            *(ushort4*)(dst + 4) = ushort4{v[4], v[5], v[6], v[7]};
        }
        return;
    }
    if (blockIdx.x == 0 && t < 128) bn[t] = 0.f;
    if (blockIdx.x < PACK_BLOCKS + 1) {
        int i = blockIdx.x * 256 + t;                     // covers 50176 >= 50000
        if (i < N_PTS) {
            float4 v;
            v.x = sp[i * 3 + 0]; v.y = sp[i * 3 + 1]; v.z = sp[i * 3 + 2]; v.w = 0.f;
            sp4[i] = v;
        }
    }
}

// ---------- K1 (k_stats): h = sf@W1 -> hst bf16 + BN sums + sfb shadow.
//            16-row tiles: 4 KB/barrier-round (was 1 KB) -> 4x fewer barriers. ----------
__global__ __launch_bounds__(256) void k_stats(const float* __restrict__ sf,
                                               const float* __restrict__ W1,
                                               float* __restrict__ bn,
                                               unsigned short* __restrict__ hst,
                                               unsigned short* __restrict__ sfb) {
    int t = threadIdx.x;
    int c = t & 63, rg = t >> 6;          // rg 0..3
    float w1c[64];
    #pragma unroll
    for (int i = 0; i < 64; ++i) w1c[i] = W1[i * 64 + c];
    __shared__ float ld[16 * 64];
    float acc_s = 0.f, acc_q = 0.f;
    for (int m0 = blockIdx.x * 16; m0 < N_PTS; m0 += STATS_BLOCKS * 16) {
        __syncthreads();
        float4 v = *(const float4*)&sf[m0 * 64 + t * 4];
        *(float4*)&ld[t * 4] = v;
        ushort2 lo = f2b2(v.x, v.y), hi = f2b2(v.z, v.w);
        *(ushort4*)&sfb[m0 * 64 + t * 4] = ushort4{lo.x, lo.y, hi.x, hi.y};
        __syncthreads();
        #pragma unroll
        for (int rr = 0; rr < 4; ++rr) {
            int r = rg + rr * 4;          // rows 0..15 across the block
            float h = 0.f;
            #pragma unroll
            for (int i4 = 0; i4 < 16; ++i4) {
                float4 rv = *(const float4*)&ld[r * 64 + i4 * 4];   // broadcast
                h += rv.x * w1c[i4 * 4] + rv.y * w1c[i4 * 4 + 1]
                   + rv.z * w1c[i4 * 4 + 2] + rv.w * w1c[i4 * 4 + 3];
            }
            acc_s += h;
            acc_q += h * h;
            hst[(m0 + r) * 64 + c] = f2b(h);      // coalesced 128B/wave
        }
    }
    __shared__ float red[2][256];
    red[0][t] = acc_s; red[1][t] = acc_q;
    __syncthreads();
    if (t < 64) {
        float s = red[0][t] + red[0][64 + t] + red[0][128 + t] + red[0][192 + t];
        float q = red[1][t] + red[1][64 + t] + red[1][128 + t] + red[1][192 + t];
        atomicAdd(&bn[t], s);
        atomicAdd(&bn[64 + t], q);
    }
}

// ---------- K2 (k_cls): neighbor classification — R12 body, standalone for attribution ----------
__global__ __launch_bounds__(256, 4) void k_cls(const float* __restrict__ q_pts,
                                                const float4* __restrict__ sp4,
                                                const int* __restrict__ nb,
                                                const float* __restrict__ kpts,
                                                unsigned* __restrict__ packG,
                                                int* __restrict__ cntG) {
    int t = threadIdx.x;
    int q0 = blockIdx.x * QC;
    int lane = t & 63, lh = lane & 31;
    __shared__ unsigned cbuf[QC * NH];   // 8 KB staging
    __shared__ int      ccnt[QC];

    // batch 1: 8 neighbor indices (coalesced)
    int idx8[8];
    #pragma unroll
    for (int r = 0; r < 8; ++r) {
        int task = t + r * 256;               // task = ql*32 + hh
        int m = q0 + (task >> 5);
        idx8[r] = (m < N_PTS) ? nb[m * NH + (task & 31)] : 0;
    }
    // batch 2: 8 float4 gathers (one txn each) + q_pts broadcasts, all in flight
    float4 sv[8]; float qx[8], qy[8], qz[8];
    #pragma unroll
    for (int r = 0; r < 8; ++r) {
        int m = q0 + ((t + r * 256) >> 5);
        int mm = (m < N_PTS) ? m : 0;
        sv[r] = sp4[idx8[r]];
        qx[r] = q_pts[mm * 3 + 0];            // 2 addrs/wave: broadcast-cheap
        qy[r] = q_pts[mm * 3 + 1];
        qz[r] = q_pts[mm * 3 + 2];
    }
    float kpr[45];
    #pragma unroll
    for (int i = 0; i < 45; ++i) kpr[i] = kpts[i];   // uniform -> s_loads

    #pragma unroll
    for (int r = 0; r < 8; ++r) {
        int task = t + r * 256;
        int ql = task >> 5;                   // local query 0..63
        bool valid = (q0 + ql < N_PTS);
        float px = sv[r].x - qx[r], py = sv[r].y - qy[r], pz = sv[r].z - qz[r];
        float best = 1e30f; int bi = 0;
        #pragma unroll
        for (int k = 0; k < KP; ++k) {
            float dx = px - kpr[k*3], dy = py - kpr[k*3+1], dz = pz - kpr[k*3+2];
            float d = dx * dx + dy * dy + dz * dz;
            if (d < best) { best = d; bi = k; }
        }
        float infl = 1.f - sqrtf(best) * (1.0f / SIGMA);
        bool act = valid && (infl > 0.f);
        unsigned long long bal = __ballot(act);
        unsigned m32 = (unsigned)(bal >> (lane & 32));   // half-wave mask
        int prefix = __popc(m32 & ((1u << lh) - 1u));
        int cntq   = __popc(m32);
        int slot   = act ? prefix : cntq + (lh - prefix);  // permutation of 0..31
        int iq = (int)(infl * 4095.f + 0.5f);
        unsigned val = act ? ((unsigned)idx8[r] | ((unsigned)bi << 16)
                              | ((unsigned)iq << 20)) : 0u;
        cbuf[ql * NH + slot] = val;           // every slot written exactly once
        if (lh == 0) ccnt[ql] = cntq;
    }
    __syncthreads();
    // coalesced writeout: 2048 dwords as 512 uint4 stores
    #pragma unroll
    for (int i = 0; i < 2; ++i) {
        int di = (t + i * 256) * 4;           // row = di>>5, uint4 stays in-row
        if (q0 + (di >> 5) < N_PTS)
            *(uint4*)(packG + q0 * NH + di) = *(const uint4*)(cbuf + di);
    }
    if (t < QC && q0 + t < N_PTS) cntG[q0 + t] = ccnt[t];
}

// ---------- K3 (k_main): fused main. 256 threads / 4 waves — proven round-3 shape. ----------
__global__ __launch_bounds__(256, 4) void k_main(
    const unsigned short* __restrict__ sfb,
    const float* __restrict__ gamma, const float* __restrict__ beta,
    const float* __restrict__ bn, const float* __restrict__ b2,
    const unsigned short* __restrict__ w2b, const unsigned short* __restrict__ hst,
    const unsigned* __restrict__ packG, const int* __restrict__ cntG,
    float* __restrict__ out) {

    __shared__ __align__(16) unsigned short cwT[960 * CWS];  // 34.56 KB: cw[n][q] bf16
    __shared__ float abS[128];                               // BN fold a[64], b[64]

    int t = threadIdx.x;
    int lane = t & 63, wv = t >> 6;
    int m0 = blockIdx.x * QB;

    if (t < 64) {   // inline BN finalize
        float mu  = bn[t] * (1.0f / N_PTS);
        float var = bn[64 + t] * (1.0f / N_PTS) - mu * mu;
        float a   = gamma[t] * rsqrtf(var + BN_EPS);
        abS[t]      = a;
        abS[64 + t] = beta[t] - mu * a;
    }
    __syncthreads();

    // ---- A-fragments directly in registers: fold BN + leaky on bf16 h rows ----
    int row = lane & 15, half = lane >> 4;
    bf16x8 a0, a1;
    {
        const unsigned short* hrow = hst + (m0 + row) * 64 + half * 8;
        bf16x8 r0 = *(const bf16x8*)(hrow);        // c = half*8 + j
        bf16x8 r1 = *(const bf16x8*)(hrow + 32);   // c = 32 + half*8 + j
        #pragma unroll
        for (int j = 0; j < 8; j += 2) {
            int c0 = half * 8 + j;
            float g0 = abS[c0] * b2f((unsigned short)r0[j]) + abS[64 + c0];
            float g1 = abS[c0 + 1] * b2f((unsigned short)r0[j + 1]) + abS[64 + c0 + 1];
            g0 = g0 > 0.f ? g0 : LEAKY * g0;
            g1 = g1 > 0.f ? g1 : LEAKY * g1;
            ushort2 p01 = f2b2(g0, g1);
            a0[j] = (short)p01.x; a0[j + 1] = (short)p01.y;
            int c1 = 32 + c0;
            float g2 = abS[c1] * b2f((unsigned short)r1[j]) + abS[64 + c1];
            float g3 = abS[c1 + 1] * b2f((unsigned short)r1[j + 1]) + abS[64 + c1 + 1];
            g2 = g2 > 0.f ? g2 : LEAKY * g2;
            g3 = g3 > 0.f ? g3 : LEAKY * g3;
            ushort2 p23 = f2b2(g2, g3);
            a1[j] = (short)p23.x; a1[j + 1] = (short)p23.y;
        }
    }

    // ---- phase A: cw = G @ W2 via MFMA; each wave owns 15 n-tiles ----
    {
        int col = lane & 15, quad = lane >> 4;
        for (int ti = 0; ti < 15; ++ti) {
            int tt = wv * 15 + ti;
            bf16x8 bf0 = *(const bf16x8*)(w2b + ((tt * 2 + 0) * 64 + lane) * 8);
            bf16x8 bf1 = *(const bf16x8*)(w2b + ((tt * 2 + 1) * 64 + lane) * 8);
            floatx4 acc = {0.f, 0.f, 0.f, 0.f};
            acc = __builtin_amdgcn_mfma_f32_16x16x32_bf16(a0, bf0, acc, 0, 0, 0);
            acc = __builtin_amdgcn_mfma_f32_16x16x32_bf16(a1, bf1, acc, 0, 0, 0);
            int n = tt * 16 + col;
            float bb = b2[n];
            unsigned short* dst = &cwT[n * CWS + quad * 4];   // D: row(q)=quad*4+reg
            ushort2 w01 = f2b2(acc[0] + bb, acc[1] + bb);     // v_cvt_pk_bf16_f32
            ushort2 w23 = f2b2(acc[2] + bb, acc[3] + bb);
            *(ushort2*)(dst)     = w01;
            *(ushort2*)(dst + 2) = w23;
        }
    }
    __syncthreads();

    // ---- phase B: wave owns 4 queries as 2 pairs; 4-wide interleave.
    //      List reads are wave-uniform (readfirstlane) -> scalar s_loads. ----
    {
        int wvu = __builtin_amdgcn_readfirstlane(wv);
        int c = lane;
        #pragma unroll
        for (int pp = 0; pp < 2; ++pp) {
            int qa = wvu * 4 + pp * 2, qb = qa + 1;
            int ma = m0 + qa, mb = m0 + qb;
            const unsigned* pA = packG + ma * NH;
            const unsigned* pB = packG + mb * NH;
            const unsigned short* cwa = cwT + c * CWS + qa;   // per-lane cw base
            const unsigned short* cwb = cwa + 1;
            int cA = cntG[ma], cB = cntG[mb];                 // uniform -> s_load
            int na = cA > cB ? cA : cB;
            na = (na + 3) & ~3;                               // slots < 32 are zeroed
            float accA = 0.f, accB = 0.f;
            for (int jj = 0; jj < na; jj += 4) {
                unsigned pa0 = pA[jj], pa1 = pA[jj+1], pa2 = pA[jj+2], pa3 = pA[jj+3];
                unsigned pb0 = pB[jj], pb1 = pB[jj+1], pb2 = pB[jj+2], pb3 = pB[jj+3];
                // 8 independent bf16 gathers (coalesced across lanes)
                float fA0 = b2f(sfb[(pa0 & 0xFFFFu) * 64 + c]);
                float fA1 = b2f(sfb[(pa1 & 0xFFFFu) * 64 + c]);
                float fA2 = b2f(sfb[(pa2 & 0xFFFFu) * 64 + c]);
                float fA3 = b2f(sfb[(pa3 & 0xFFFFu) * 64 + c]);
                float fB0 = b2f(sfb[(pb0 & 0xFFFFu) * 64 + c]);
                float fB1 = b2f(sfb[(pb1 & 0xFFFFu) * 64 + c]);
                float fB2 = b2f(sfb[(pb2 & 0xFFFFu) * 64 + c]);
                float fB3 = b2f(sfb[(pb3 & 0xFFFFu) * 64 + c]);
                // 8 LDS reads (k*64*CWS offset from scalar field)
                float wA0 = b2f(cwa[((pa0 >> 16) & 15u) * (64 * CWS)]);
                float wA1 = b2f(cwa[((pa1 >> 16) & 15u) * (64 * CWS)]);
                float wA2 = b2f(cwa[((pa2 >> 16) & 15u) * (64 * CWS)]);
                float wA3 = b2f(cwa[((pa3 >> 16) & 15u) * (64 * CWS)]);
                float wB0 = b2f(cwb[((pb0 >> 16) & 15u) * (64 * CWS)]);
                float wB1 = b2f(cwb[((pb1 >> 16) & 15u) * (64 * CWS)]);
                float wB2 = b2f(cwb[((pb2 >> 16) & 15u) * (64 * CWS)]);
                float wB3 = b2f(cwb[((pb3 >> 16) & 15u) * (64 * CWS)]);
                // q12 influence from scalar field
                float iA0 = (float)(pa0 >> 20), iA1 = (float)(pa1 >> 20);
                float iA2 = (float)(pa2 >> 20), iA3 = (float)(pa3 >> 20);
                float iB0 = (float)(pb0 >> 20), iB1 = (float)(pb1 >> 20);
                float iB2 = (float)(pb2 >> 20), iB3 = (float)(pb3 >> 20);
                accA += iA0 * fA0 * wA0 + iA1 * fA1 * wA1
                      + iA2 * fA2 * wA2 + iA3 * fA3 * wA3;
                accB += iB0 * fB0 * wB0 + iB1 * fB1 * wB1
                      + iB2 * fB2 * wB2 + iB3 * fB3 * wB3;
            }
            const float qs = 1.f / 4095.f;
            out[ma * 64 + c] = accA * qs;
            out[mb * 64 + c] = accB * qs;
        }
    }
}

extern "C" void kernel_launch(void* const* d_in, const int* in_sizes, int n_in,
                              void* d_out, int out_size, void* d_ws, size_t ws_size,
                              hipStream_t stream) {
    const float* q_pts   = (const float*)d_in[0];
    const float* s_pts   = (const float*)d_in[1];
    const float* s_feats = (const float*)d_in[2];
    const int*   nb      = (const int*)d_in[3];
    const float* kpts    = (const float*)d_in[4];
    const float* W1      = (const float*)d_in[5];
    const float* gamma   = (const float*)d_in[6];
    const float* beta    = (const float*)d_in[7];
    const float* W2      = (const float*)d_in[8];
    const float* b2      = (const float*)d_in[9];
    float* out = (float*)d_out;

    float* ws = (float*)d_ws;
    float* bn = ws;                                        // 128 fp32
    unsigned short* w2b = (unsigned short*)(ws + 128);     // 61440 bf16 (122880 B)
    unsigned short* hst = w2b + 61440;                     // 50000*64 bf16 (6.4 MB)
    unsigned short* sfb = hst + N_PTS * CCH;               // 50000*64 bf16 (6.4 MB)
    unsigned* packG = (unsigned*)(sfb + N_PTS * CCH);      // 50000*32 u32 (6.4 MB)
    int* cntG = (int*)(packG + N_PTS * NH);                // 50000 int (200 KB)
    float4* sp4 = (float4*)(cntG + ((N_PTS + 3) & ~3));    // 50000 float4 (800 KB)

    k_misc<<<PACK_BLOCKS + 1 + 60, 256, 0, stream>>>(s_pts, W2, sp4, w2b, bn);
    k_stats<<<STATS_BLOCKS, 256, 0, stream>>>(s_feats, W1, bn, hst, sfb);
    k_cls<<<CLS_BLOCKS, 256, 0, stream>>>(q_pts, sp4, nb, kpts, packG, cntG);
    k_main<<<N_PTS / QB, 256, 0, stream>>>(sfb, gamma, beta, bn, b2, w2b, hst,
                                           packG, cntG, out);
}